// Round 7
// baseline (1550.717 us; speedup 1.0000x reference)
//
#include <hip/hip_runtime.h>
#include <math.h>

#define CC 64
#define HW 4096
#define NB 4
#define NT 10

#define WTA_SZ (64*9*128)   // repacked rz weights [ic*9+k][128] (z|r in low/high 64)
#define WTT_SZ (64*9)       // thr weights [ic*9+k]
#define WTB_SZ (64*9*64)    // repacked f weights [ic*9+k][64]

__device__ __forceinline__ float sigm(float x) { return 1.0f / (1.0f + expf(-x)); }

#define LD4(dst, src) do { float4 _t = *(const float4*)(src); \
    (dst)[0]=_t.x; (dst)[1]=_t.y; (dst)[2]=_t.z; (dst)[3]=_t.w; } while(0)

// One halo row for col-quarter Q. Slot s <-> img col (c0-4+s); used slots 3..20.
// Q==0: cols<0 zeroed, loads start at col 0 (no OOB). Q==3: col 64 zeroed, no
// load past col 63 (no OOB). All branches compile-time.
template<int Q>
__device__ __forceinline__ void load_row(float (&W)[24], const float* __restrict__ rp, int c0) {
    if (Q == 0) {
        W[3] = 0.f;
        LD4(W+4,  rp);      LD4(W+8,  rp+4);   LD4(W+12, rp+8);
        LD4(W+16, rp+12);   LD4(W+20, rp+16);
    } else if (Q == 3) {
        const float* s = rp + c0 - 4;
        LD4(W+0, s);   LD4(W+4, s+4);   LD4(W+8, s+8);
        LD4(W+12, s+12); LD4(W+16, s+16);
        W[20] = 0.f;
    } else {
        const float* s = rp + c0 - 4;
        LD4(W+0, s);   LD4(W+4, s+4);   LD4(W+8, s+8);
        LD4(W+12, s+12); LD4(W+16, s+16); LD4(W+20, s+20);
    }
}

__device__ __forceinline__ void zero_row(float (&W)[24]) {
#pragma unroll
    for (int j = 3; j <= 20; ++j) W[j] = 0.f;
}

// 16 px x 9 taps; weights per-lane (lane = oc), window broadcast.
__device__ __forceinline__ void fma144(const float (&w)[9], const float (&W)[3][24],
                                       float (&acc)[16]) {
#pragma unroll
    for (int p = 0; p < 16; ++p) {
        float s = acc[p];
        s = fmaf(w[0], W[0][3+p], s);
        s = fmaf(w[1], W[0][4+p], s);
        s = fmaf(w[2], W[0][5+p], s);
        s = fmaf(w[3], W[1][3+p], s);
        s = fmaf(w[4], W[1][4+p], s);
        s = fmaf(w[5], W[1][5+p], s);
        s = fmaf(w[6], W[2][3+p], s);
        s = fmaf(w[7], W[2][4+p], s);
        s = fmaf(w[8], W[2][5+p], s);
        acc[p] = s;
    }
}

// Main conv loop: NIC input channels starting at img / weight index wick0.
// wb = transposed weight base + lane (per-lane VGPR loads, coalesced 256B).
// Weight ping-pong; window loads covered by TLP. All VMEM domain.
template<int Q, int NIC, int OCW>
__device__ __forceinline__ void conv_loop(float (&acc)[16],
        const float* __restrict__ img, const float* __restrict__ wb,
        int wick0, int row, int c0)
{
    float wv0[9], wv1[9];
#pragma unroll
    for (int k = 0; k < 9; ++k) wv0[k] = wb[(size_t)(wick0 + k) * OCW];
    const int ro0 = (row - 1) * 64, ro1 = row * 64, ro2 = (row + 1) * 64;
    const bool rok0 = row >= 1, rok2 = row <= 62;
    const float* pc = img;
    int wick = wick0 + 9;
    float W[3][24];
#pragma unroll 1
    for (int ic2 = 0; ic2 < NIC; ic2 += 2) {
#pragma unroll
        for (int k = 0; k < 9; ++k) wv1[k] = wb[(size_t)(wick + k) * OCW];
        if (rok0) load_row<Q>(W[0], pc + ro0, c0); else zero_row(W[0]);
        load_row<Q>(W[1], pc + ro1, c0);
        if (rok2) load_row<Q>(W[2], pc + ro2, c0); else zero_row(W[2]);
        fma144(wv0, W, acc);
        if (ic2 + 2 < NIC) {
#pragma unroll
            for (int k = 0; k < 9; ++k) wv0[k] = wb[(size_t)(wick + 9 + k) * OCW];
        }
        const float* pc1 = pc + HW;
        if (rok0) load_row<Q>(W[0], pc1 + ro0, c0); else zero_row(W[0]);
        load_row<Q>(W[1], pc1 + ro1, c0);
        if (rok2) load_row<Q>(W[2], pc1 + ro2, c0); else zero_row(W[2]);
        fma144(wv1, W, acc);
        pc += 2 * HW;
        wick += 18;
    }
}

// One-time weight repack: [oc][ic][k] -> [ic*9+k][oc]. All writes bounds-checked
// against limit (floats) so a tight workspace cannot memory-fault.
__global__ void repack_kernel(const float* __restrict__ w_rz,
                              const float* __restrict__ w_f,
                              float* __restrict__ wbase,
                              unsigned int limit) {
    unsigned int i = blockIdx.x * blockDim.x + threadIdx.x;
    if (i >= (unsigned int)(WTA_SZ + WTT_SZ + WTB_SZ) || i >= limit) return;
    float v;
    if (i < WTA_SZ) {
        unsigned int oc = i & 127, ick = i >> 7;
        v = w_rz[(size_t)oc * 576 + ick];
    } else if (i < WTA_SZ + WTT_SZ) {
        unsigned int j = i - WTA_SZ;
        v = w_rz[(size_t)128 * 576 + j];
    } else {
        unsigned int j = i - WTA_SZ - WTT_SZ;
        unsigned int oc = j & 63, ick = j >> 6;
        v = w_f[(size_t)oc * 576 + ick];
    }
    wbase[i] = v;
}

// ---------------------------------------------------------------------------
// Kernel A: rz = conv3x3(prev_y, w_rz) + b_rz (129 ch). oc-per-lane.
// Block (b,row): 9 waves. Waves 0-7 = (q colquarter, g z/r): 16px x 64oc x 64ic,
// no LDS/barrier in main loop. Wave 8 = thr channel (shfl halo). Epilogue:
// LDS transpose [128][68] -> coalesced gate stores.
// ---------------------------------------------------------------------------
__global__ __launch_bounds__(576, 1) void convA_kernel(
    const float* __restrict__ prev_y,
    const float* __restrict__ xt_t,
    const float* __restrict__ wT,
    const float* __restrict__ wt_thr,
    const float* __restrict__ b_rz,
    float* __restrict__ ws_u,
    float* __restrict__ ws_ry,
    float* __restrict__ ws_thr,
    int first)
{
    __shared__ float lds[128 * 68];
    const int tid  = threadIdx.x;
    const int wid  = tid >> 6;            // 0..8
    const int lane = tid & 63;
    const int b    = blockIdx.x;
    const int row  = blockIdx.y;

    if (wid < 8) {
        const int q  = wid & 3;
        const int g  = wid >> 2;          // 0=z, 1=r
        const int c0 = q * 16;
        float acc[16];
#pragma unroll
        for (int p = 0; p < 16; ++p) acc[p] = 0.f;
        if (!first) {
            const float* img = prev_y + (size_t)b * CC * HW;
            const float* wb  = wT + g * 64 + lane;
            switch (q) {
                case 0:  conv_loop<0, 64, 128>(acc, img, wb, 0, row, c0); break;
                case 3:  conv_loop<3, 64, 128>(acc, img, wb, 0, row, c0); break;
                default: conv_loop<1, 64, 128>(acc, img, wb, 0, row, c0); break;
            }
        }
        float* dst = lds + (g * 64 + lane) * 68 + c0;   // 68-pad: 16B-aligned rows
        *(float4*)(dst)      = make_float4(acc[0],  acc[1],  acc[2],  acc[3]);
        *(float4*)(dst + 4)  = make_float4(acc[4],  acc[5],  acc[6],  acc[7]);
        *(float4*)(dst + 8)  = make_float4(acc[8],  acc[9],  acc[10], acc[11]);
        *(float4*)(dst + 12) = make_float4(acc[12], acc[13], acc[14], acc[15]);
    } else {
        // thr channel (oc 128): lane = col, shfl halo, s_load weights.
        float acct = 0.f;
        if (!first) {
            const float* img = prev_y + (size_t)b * CC * HW;
            const int ro[3] = {(row - 1) * 64, row * 64, (row + 1) * 64};
            const bool rok[3] = {row >= 1, true, row <= 62};
#pragma unroll 1
            for (int ic = 0; ic < 64; ++ic) {
                const float* pc  = img + (size_t)ic * HW;
                const float* wt9 = wt_thr + ic * 9;
#pragma unroll
                for (int r = 0; r < 3; ++r) {
                    float v  = rok[r] ? pc[ro[r] + lane] : 0.f;
                    float vl = __shfl_up(v, 1);
                    float vr = __shfl_down(v, 1);
                    if (lane == 0)  vl = 0.f;
                    if (lane == 63) vr = 0.f;
                    acct = fmaf(wt9[r*3+0], vl, acct);
                    acct = fmaf(wt9[r*3+1], v,  acct);
                    acct = fmaf(wt9[r*3+2], vr, acct);
                }
            }
        }
        ws_thr[(size_t)b * HW + row * 64 + lane] = sigm(acct + b_rz[2 * CC]);
    }
    __syncthreads();
    if (wid < 8) {
        const int col = lane;
        const size_t pix = (size_t)row * 64 + col;
        if (wid < 4) {                    // z ocs: wid*16 .. wid*16+15
#pragma unroll 1
            for (int j = 0; j < 16; ++j) {
                const int oc = wid * 16 + j;
                float v = lds[oc * 68 + col];
                float u = sigm(v + b_rz[oc] + xt_t[((size_t)b * 192 + oc) * HW + pix]);
                ws_u[((size_t)b * CC + oc) * HW + pix] = u;
            }
        } else {                          // r ocs: 64 + (wid-4)*16 ..
#pragma unroll 1
            for (int j = 0; j < 16; ++j) {
                const int oc = 64 + (wid - 4) * 16 + j;
                const int ch = oc - 64;
                float v = lds[oc * 68 + col];
                float gate = sigm(v + b_rz[oc] + xt_t[((size_t)b * 192 + oc) * HW + pix]);
                float py = first ? 0.f : prev_y[((size_t)b * CC + ch) * HW + pix];
                ws_ry[((size_t)b * CC + ch) * HW + pix] = py * gate;
            }
        }
    }
}

// ---------------------------------------------------------------------------
// Kernel B: f = conv3x3(ry, w_f) + b_f + xi_f ; fused GRU update + spike.
// Block (b,row): 8 waves = (q colquarter, ks ic-half). Split-K combined in the
// LDS transpose. Epilogue: 8 waves x 8 oc, coalesced.
// ---------------------------------------------------------------------------
__global__ __launch_bounds__(512, 1) void convB_kernel(
    const float* __restrict__ ry,
    const float* __restrict__ xt_t,
    const float* __restrict__ wTf,
    const float* __restrict__ b_f,
    const float* __restrict__ ws_u,
    const float* __restrict__ ws_thr,
    float* __restrict__ ws_h,
    float* __restrict__ out_y,
    float* __restrict__ out_e,
    float* __restrict__ out_nd,
    int first)
{
    __shared__ float lds[128 * 68];
    const int tid  = threadIdx.x;
    const int wid  = tid >> 6;            // 0..7
    const int lane = tid & 63;
    const int b    = blockIdx.x;
    const int row  = blockIdx.y;
    const int q    = wid & 3;
    const int ks   = wid >> 2;
    const int c0   = q * 16;

    float acc[16];
#pragma unroll
    for (int p = 0; p < 16; ++p) acc[p] = 0.f;
    if (!first) {                         // ry == 0 at t==0 -> conv is 0
        const float* img = ry + (size_t)b * CC * HW + (size_t)ks * 32 * HW;
        const float* wb  = wTf + lane;
        const int wick0  = ks * 32 * 9;
        switch (q) {
            case 0:  conv_loop<0, 32, 64>(acc, img, wb, wick0, row, c0); break;
            case 3:  conv_loop<3, 32, 64>(acc, img, wb, wick0, row, c0); break;
            default: conv_loop<1, 32, 64>(acc, img, wb, wick0, row, c0); break;
        }
    }
    float* dst = lds + (ks * 64 + lane) * 68 + c0;
    *(float4*)(dst)      = make_float4(acc[0],  acc[1],  acc[2],  acc[3]);
    *(float4*)(dst + 4)  = make_float4(acc[4],  acc[5],  acc[6],  acc[7]);
    *(float4*)(dst + 8)  = make_float4(acc[8],  acc[9],  acc[10], acc[11]);
    *(float4*)(dst + 12) = make_float4(acc[12], acc[13], acc[14], acc[15]);
    __syncthreads();

    // epilogue: GRU update + spike, 8 oc per wave, lane = col
    const int col = lane;
    const size_t pix = (size_t)row * 64 + col;
    const float tt = ws_thr[(size_t)b * HW + pix];
#pragma unroll 1
    for (int j = 0; j < 8; ++j) {
        const int oc = wid * 8 + j;
        float v  = lds[oc * 68 + col] + lds[(64 + oc) * 68 + col];
        float fx = v + b_f[oc] + xt_t[((size_t)b * 192 + 2 * CC + oc) * HW + pix];
        const size_t coff = ((size_t)b * CC + oc) * HW + pix;
        float u  = ws_u[coff];
        float h  = first ? 0.f : ws_h[coff];
        float ig = tanhf(fx);
        float hn = (1.f - u) * h + u * ig;
        float d  = hn - tt;
        bool pos = d > 0.f;
        out_y[coff]  = pos ? hn : 0.f;
        out_e[coff]  = pos ? 1.f : 0.f;
        out_nd[coff] = (d < 0.f) ? (tt - hn) : 0.f;
        ws_h[coff]   = pos ? (hn - tt) : hn;
    }
}

extern "C" void kernel_launch(void* const* d_in, const int* in_sizes, int n_in,
                              void* d_out, int out_size, void* d_ws, size_t ws_size,
                              hipStream_t stream) {
    const float* xt   = (const float*)d_in[0];
    const float* w_rz = (const float*)d_in[1];
    const float* b_rz = (const float*)d_in[2];
    const float* w_f  = (const float*)d_in[3];
    const float* b_f  = (const float*)d_in[4];
    float* out = (float*)d_out;
    float* ws  = (float*)d_ws;

    const size_t NCHW = (size_t)NB * CC * HW;   // 1,048,576 floats
    // Layout: [wT_rz | wt_thr | wT_f | ws_u | ws_ry | ws_thr | ws_h]
    const size_t WTOT = (size_t)WTA_SZ + WTT_SZ + WTB_SZ;
    float* wT_rz  = ws;
    float* wt_thr = ws + WTA_SZ;
    float* wT_f   = ws + WTA_SZ + WTT_SZ;
    float* ws_u   = ws + WTOT;
    float* ws_ry  = ws_u + NCHW;
    float* ws_thr = ws_ry + NCHW;
    float* ws_h   = ws_thr + (size_t)NB * HW;

    float* ys  = out;
    float* es  = out + (size_t)NT * NCHW;
    float* nds = out + 2 * (size_t)NT * NCHW;

    // Bounds-guard the repack so a tight workspace cannot memory-fault.
    const unsigned int limit =
        (unsigned int)(ws_size / sizeof(float) > WTOT ? WTOT : ws_size / sizeof(float));
    hipLaunchKernelGGL(repack_kernel, dim3(((int)WTOT + 255) / 256), dim3(256), 0, stream,
                       w_rz, w_f, ws, limit);

    for (int t = 0; t < NT; ++t) {
        const float* xtt = xt + (size_t)t * NB * 192 * HW;
        const float* py  = (t == 0) ? xtt : (ys + (size_t)(t - 1) * NCHW);
        hipLaunchKernelGGL(convA_kernel, dim3(NB, 64), dim3(576), 0, stream,
                           py, xtt, wT_rz, wt_thr, b_rz, ws_u, ws_ry, ws_thr, (t == 0) ? 1 : 0);
        hipLaunchKernelGGL(convB_kernel, dim3(NB, 64), dim3(512), 0, stream,
                           ws_ry, xtt, wT_f, b_f, ws_u, ws_thr, ws_h,
                           ys + (size_t)t * NCHW, es + (size_t)t * NCHW,
                           nds + (size_t)t * NCHW, (t == 0) ? 1 : 0);
    }
}